// Round 19
// baseline (67.643 us; speedup 1.0000x reference)
//
#include <hip/hip_runtime.h>

#define BATCH 4
#define NS    512
#define XS    1024

#define NT    2048
#define RMAX  96.0f
#define HSTEP (RMAX / (float)NT)
#define INVH  ((float)NT / RMAX)

#define C2   2.8853900817779268f   // 2*log2(e)
#define NBLK 512
#define NCTR 64                    // arrival counters (8 blocks each)

typedef float f32x4 __attribute__((ext_vector_type(4)));

__device__ __forceinline__ float bcast(float v, int lane) {   // compile-time lane
    return __builtin_bit_cast(float, __builtin_amdgcn_readlane(__builtin_bit_cast(int, v), lane));
}

// Single kernel node (+256B memset node): 512 blocks x 512 threads, 2/CU resident.
//  Phase A: waves 0..3 build K[bid*4+wv]; agent-scope (sc-bit) stores -> IC holds fresh K.
//  Barrier: cnt[bid&63] fetch_add, wave-0 relaxed polls (NO invalidates - R14 lesson).
//  Visibility: ONE agent acquire-fence per block, then NORMAL cached dwordx4 copy of K
//              (first block/XCD refills L2 from IC; other ~63 blocks L2-hit - R18 lesson).
//  Phase B: wave wv integrates xp = bid*8+wv from the LDS table.
extern "C" __global__ __launch_bounds__(512, 4)
void neurop_one(const float* __restrict__ yu, const float* __restrict__ x,
                const float* __restrict__ W_in, const float* __restrict__ b_in,
                const float* __restrict__ W_h, const float* __restrict__ b_h,
                const float* __restrict__ W_out, const float* __restrict__ b_out,
                float* __restrict__ K, unsigned int* __restrict__ cnt,
                float* __restrict__ out)
{
    __shared__ float kl[NT];
    const int t   = threadIdx.x;
    const int l   = t & 63;
    const int wv  = t >> 6;
    const int bid = blockIdx.x;

    // ---------------- Phase A: waves 0..3 build K[bid*4+wv] ----------------
    if (wv < 4) {
        const int e  = bid * 4 + wv;
        const float r = (float)e * HSTEP;
        float h = fmaf(r, W_in[l], b_in[l]);

        #pragma unroll 1
        for (int d = 0; d < 6; ++d) {
            const float* __restrict__ W = W_h + (d << 12);   // W[i][j] row-major
            float hn = b_h[(d << 6) + l];
            #pragma unroll
            for (int i = 0; i < 64; ++i)
                hn = fmaf(bcast(h, i), W[(i << 6) + l], hn); // coalesced across lanes
            float ex = __builtin_amdgcn_exp2f(C2 * hn);      // tanh(z)=1-2/(exp2(C2 z)+1)
            float rc = __builtin_amdgcn_rcpf(ex + 1.0f);
            h = fmaf(-2.0f, rc, h + 1.0f);
        }

        float p = h * W_out[l];
        #pragma unroll
        for (int off = 1; off < 64; off <<= 1)
            p += __shfl_xor(p, off);
        if (l == 0)
            __hip_atomic_store(&K[e], p + b_out[0],
                               __ATOMIC_RELAXED, __HIP_MEMORY_SCOPE_AGENT);
    }
    __syncthreads();   // s_waitcnt vmcnt(0) before s_barrier: K stores acked at IC

    // ---------------- low-contention arrival + relaxed spin ----------------
    if (t == 0)
        __hip_atomic_fetch_add(&cnt[bid & (NCTR - 1)], 1u,
                               __ATOMIC_RELAXED, __HIP_MEMORY_SCOPE_AGENT);
    if (wv == 0) {
        for (;;) {
            unsigned int v = __hip_atomic_load(&cnt[l & (NCTR - 1)],
                                               __ATOMIC_RELAXED, __HIP_MEMORY_SCOPE_AGENT);
            if (__all(v >= NBLK / NCTR)) break;
            __builtin_amdgcn_s_sleep(16);
        }
    }
    __syncthreads();

    // ---------------- one acquire-fence per block, then CACHED copy ----------------
    __builtin_amdgcn_fence(__ATOMIC_ACQUIRE, "agent");   // L1/L2 inv: next reads see IC
    {
        f32x4 kv = *(const f32x4*)(K + t * 4);           // normal dwordx4: L2-shared refill
        *(f32x4*)&kl[t * 4] = kv;
    }
    __syncthreads();

    // ---------------- Phase B: integrate xp = bid*8+wv ----------------
    {
        const int xp = bid * 8 + wv;       // b*XS + xi
        const int b  = xp >> 10;
        const float x0 = x[xp * 2 + 0];
        const float x1 = x[xp * 2 + 1];

        float a0 = 0.0f, a1 = 0.0f, a2 = 0.0f;
        #pragma unroll
        for (int c = 0; c < 8; ++c) {
            const int s = c * 64 + l;
            const float* ur = yu + (b * NS + s) * 5;
            f32x4 uy;                      // u0,u1,u2,y0 (4B-aligned 16B load)
            __builtin_memcpy(&uy, ur, 16);
            const float y1v = ur[4];
            const float d0 = x0 - uy.w, d1 = x1 - y1v;
            const float r  = d0 * d0 + d1 * d1;

            float tt = fminf(r * INVH, (float)NT - 1.5f);   // i <= NT-2
            int   i  = (int)tt;
            float f  = tt - (float)i;
            float k0 = kl[i], k1 = kl[i + 1];
            float k  = fmaf(f, k1 - k0, k0);

            a0 = fmaf(k, uy.x, a0);
            a1 = fmaf(k, uy.y, a1);
            a2 = fmaf(k, uy.z, a2);
        }
        #pragma unroll
        for (int off = 1; off < 64; off <<= 1) {
            a0 += __shfl_xor(a0, off);
            a1 += __shfl_xor(a1, off);
            a2 += __shfl_xor(a2, off);
        }
        if (l == 0) {
            out[xp * 3 + 0] = a0 * (1.0f / (float)NS);
            out[xp * 3 + 1] = a1 * (1.0f / (float)NS);
            out[xp * 3 + 2] = a2 * (1.0f / (float)NS);
        }
    }
}

extern "C" void kernel_launch(void* const* d_in, const int* in_sizes, int n_in,
                              void* d_out, int out_size, void* d_ws, size_t ws_size,
                              hipStream_t stream) {
    const float* yu    = (const float*)d_in[0];
    const float* x     = (const float*)d_in[1];
    const float* W_in  = (const float*)d_in[2];
    const float* b_in  = (const float*)d_in[3];
    const float* W_h   = (const float*)d_in[4];
    const float* b_h   = (const float*)d_in[5];
    const float* W_out = (const float*)d_in[6];
    const float* b_out = (const float*)d_in[7];
    float* out = (float*)d_out;
    float*        K   = (float*)d_ws;                         // 2048*4 = 8 KB
    unsigned int* cnt = (unsigned int*)((char*)d_ws + 8192);  // 64*4 = 256 B

    (void)hipMemsetAsync(cnt, 0, NCTR * sizeof(unsigned int), stream);
    hipLaunchKernelGGL(neurop_one, dim3(NBLK), dim3(512), 0, stream,
                       yu, x, W_in, b_in, W_h, b_h, W_out, b_out, K, cnt, out);
}

// Round 20
// 21.310 us; speedup vs baseline: 3.1741x; 3.1741x over previous
//
#include <hip/hip_runtime.h>

#define BATCH 4
#define NS    512
#define XS    1024

#define NT    2048
#define RMAX  96.0f
#define HSTEP (RMAX / (float)NT)
#define INVH  ((float)NT / RMAX)

#define C2 2.8853900817779268f   // 2*log2(e)

typedef float f32x4 __attribute__((ext_vector_type(4)));

__device__ __forceinline__ float bcast(float v, int lane) {   // compile-time lane
    return __builtin_bit_cast(float, __builtin_amdgcn_readlane(__builtin_bit_cast(int, v), lane));
}

// ---- Kernel 1: tabulate k(r); one wave per TWO entries, one lane per feature.
//      Column loads W[(i<<6)+j]: lanes contiguous in j -> fully coalesced. ----
extern "C" __global__ __launch_bounds__(512)
void build_k_table(const float* __restrict__ W_in,
                   const float* __restrict__ b_in,
                   const float* __restrict__ W_h,
                   const float* __restrict__ b_h,
                   const float* __restrict__ W_out,
                   const float* __restrict__ b_out,
                   float* __restrict__ K)
{
    const int wv = threadIdx.x >> 6;            // wave in block
    const int j  = threadIdx.x & 63;            // feature owned by this lane
    const int e0 = (blockIdx.x * 8 + wv) * 2;   // first of two entries
    const float r0 = (float)e0 * HSTEP;
    const float r1 = (float)(e0 + 1) * HSTEP;

    const float wi = W_in[j], bi = b_in[j];
    float h0 = fmaf(r0, wi, bi);
    float h1 = fmaf(r1, wi, bi);

    #pragma unroll 1
    for (int d = 0; d < 6; ++d) {
        const float* __restrict__ W = W_h + (d << 12);   // W[i][j], row-major
        const float bb = b_h[(d << 6) + j];
        float hn0 = bb, hn1 = bb;
        #pragma unroll
        for (int i = 0; i < 64; ++i) {
            float w = W[(i << 6) + j];                   // coalesced across lanes
            hn0 = fmaf(bcast(h0, i), w, hn0);
            hn1 = fmaf(bcast(h1, i), w, hn1);
        }
        // h += tanh(hn):  tanh(z) = 1 - 2/(exp2(C2*z)+1)
        float ex0 = __builtin_amdgcn_exp2f(C2 * hn0);
        float ex1 = __builtin_amdgcn_exp2f(C2 * hn1);
        float rc0 = __builtin_amdgcn_rcpf(ex0 + 1.0f);
        float rc1 = __builtin_amdgcn_rcpf(ex1 + 1.0f);
        h0 = fmaf(-2.0f, rc0, h0 + 1.0f);
        h1 = fmaf(-2.0f, rc1, h1 + 1.0f);
    }

    const float wo = W_out[j];
    float p0 = h0 * wo, p1 = h1 * wo;
    #pragma unroll
    for (int off = 1; off < 64; off <<= 1) {
        p0 += __shfl_xor(p0, off);
        p1 += __shfl_xor(p1, off);
    }
    if (j == 0) {
        const float bo = b_out[0];
        K[e0]     = p0 + bo;
        K[e0 + 1] = p1 + bo;
    }
}

// ---- Kernel 2: one WAVE per x-point; 8 sensors per lane, local accumulate ----
extern "C" __global__ __launch_bounds__(256)
void integrate(const float* __restrict__ yu, const float* __restrict__ x,
               const float* __restrict__ K, float* __restrict__ out)
{
    const int t  = threadIdx.x;
    const int wv = t >> 6, l = t & 63;
    const int xp = blockIdx.x * 4 + wv;       // b*XS + xi
    const int b  = xp >> 10;

    const float x0 = x[xp * 2 + 0];
    const float x1 = x[xp * 2 + 1];

    float a0 = 0.0f, a1 = 0.0f, a2 = 0.0f;
    #pragma unroll
    for (int c = 0; c < 8; ++c) {
        const int s = c * 64 + l;
        const float* ur = yu + (b * NS + s) * 5;
        f32x4 uy;                              // u0,u1,u2,y0 (4B-aligned 16B load)
        __builtin_memcpy(&uy, ur, 16);
        const float y1v = ur[4];
        const float d0 = x0 - uy.w, d1 = x1 - y1v;
        const float r  = d0 * d0 + d1 * d1;

        float tt = fminf(r * INVH, (float)NT - 1.5f);   // i <= NT-2
        int   i  = (int)tt;
        float f  = tt - (float)i;
        float k0 = K[i], k1 = K[i + 1];
        float k  = fmaf(f, k1 - k0, k0);

        a0 = fmaf(k, uy.x, a0);
        a1 = fmaf(k, uy.y, a1);
        a2 = fmaf(k, uy.z, a2);
    }
    #pragma unroll
    for (int off = 1; off < 64; off <<= 1) {
        a0 += __shfl_xor(a0, off);
        a1 += __shfl_xor(a1, off);
        a2 += __shfl_xor(a2, off);
    }
    if (l == 0) {
        out[xp * 3 + 0] = a0 * (1.0f / (float)NS);
        out[xp * 3 + 1] = a1 * (1.0f / (float)NS);
        out[xp * 3 + 2] = a2 * (1.0f / (float)NS);
    }
}

extern "C" void kernel_launch(void* const* d_in, const int* in_sizes, int n_in,
                              void* d_out, int out_size, void* d_ws, size_t ws_size,
                              hipStream_t stream) {
    const float* yu    = (const float*)d_in[0];
    const float* x     = (const float*)d_in[1];
    const float* W_in  = (const float*)d_in[2];
    const float* b_in  = (const float*)d_in[3];
    const float* W_h   = (const float*)d_in[4];
    const float* b_h   = (const float*)d_in[5];
    const float* W_out = (const float*)d_in[6];
    const float* b_out = (const float*)d_in[7];
    float* out = (float*)d_out;
    float* K   = (float*)d_ws;    // NT * 4 = 8 KB

    hipLaunchKernelGGL(build_k_table, dim3(NT / 16), dim3(512), 0, stream,
                       W_in, b_in, W_h, b_h, W_out, b_out, K);
    hipLaunchKernelGGL(integrate, dim3(BATCH * XS / 4), dim3(256), 0, stream,
                       yu, x, (const float*)K, out);
}